// Round 2
// baseline (132.470 us; speedup 1.0000x reference)
//
#include <hip/hip_runtime.h>
#include <cstdint>

typedef __attribute__((ext_vector_type(8))) short bf16x8;
typedef __attribute__((ext_vector_type(4))) float f32x4;

#if __has_builtin(__builtin_amdgcn_exp2f)
#define EXP2F(x) __builtin_amdgcn_exp2f(x)
#else
#define EXP2F(x) exp2f(x)
#endif
#if __has_builtin(__builtin_amdgcn_rcpf)
#define RCPF(x) __builtin_amdgcn_rcpf(x)
#else
#define RCPF(x) (1.0f/(x))
#endif

#define C2LOG2E 2.885390081777927f   // 2*log2(e)
#define LOG2E   1.4426950408889634f

__device__ __forceinline__ unsigned short f2bf(float f) {
    union { float f; unsigned int u; } v; v.f = f;
    return (unsigned short)((v.u + 0x7FFFu + ((v.u >> 16) & 1u)) >> 16);
}
__device__ __forceinline__ float bf2f(unsigned short h) {
    union { unsigned int u; float f; } v; v.u = ((unsigned int)h) << 16; return v.f;
}

// ---------------- prep: X fp32->bf16 ; W_ap transpose ----------------
__global__ void prep_kernel(const float* __restrict__ x, const float* __restrict__ W_ap,
                            unsigned short* __restrict__ Xb, float* __restrict__ Wt) {
    int t = blockIdx.x * 256 + threadIdx.x;   // 32768 threads, 8 elems each
    const float* src = x + (size_t)t * 8;
    float4 a = *(const float4*)(src);
    float4 b = *(const float4*)(src + 4);
    unsigned int p0 = (unsigned int)f2bf(a.x) | ((unsigned int)f2bf(a.y) << 16);
    unsigned int p1 = (unsigned int)f2bf(a.z) | ((unsigned int)f2bf(a.w) << 16);
    unsigned int p2 = (unsigned int)f2bf(b.x) | ((unsigned int)f2bf(b.y) << 16);
    unsigned int p3 = (unsigned int)f2bf(b.z) | ((unsigned int)f2bf(b.w) << 16);
    *(int4*)(Xb + (size_t)t * 8) = make_int4((int)p0, (int)p1, (int)p2, (int)p3);
    if (t < 64 * 64) Wt[t] = W_ap[(t & 63) * 64 + (t >> 6)];  // Wt[o][d] = W_ap[d][o]
}

// ---------------- main: one block per (b,i), X read from global (L2-hot) ----------------
__global__ __launch_bounds__(256, 4) void gat_kernel(
    const float* __restrict__ x, const float* __restrict__ b_ap, const float* __restrict__ att_w,
    const float* __restrict__ W_pa, const float* __restrict__ b_pa,
    const float* __restrict__ W_po, const float* __restrict__ b_po,
    const float* __restrict__ gma, const float* __restrict__ bta,
    const float* __restrict__ rmean, const float* __restrict__ rvar,
    const unsigned short* __restrict__ Xb, const float* __restrict__ Wt,
    float* __restrict__ out)
{
    __shared__ char  sWF[8192];     // W_i MFMA A-fragments (bf16); reused as agg partials
    __shared__ float sSc[512];      // scores -> p
    __shared__ float sXi[64];
    __shared__ float sAw[64];       // att_w staged
    __shared__ float sBp[64];       // b_ap staged
    __shared__ float sAg[64];
    __shared__ float sRd[8];

    const int t = threadIdx.x;
    const int l = t & 63;
    const int w = t >> 6;
    const int bid = blockIdx.x;
    const int b = bid >> 9;
    const unsigned short* __restrict__ Xg = Xb + (size_t)b * (512 * 64);

    // ---- stage x_i, att_w, b_ap ----
    if (t < 64)            sXi[t]       = x[((size_t)bid << 6) + t];
    else if (t < 128)      sAw[t - 64]  = att_w[t - 64];
    else if (t < 192)      sBp[t - 128] = b_ap[t - 128];
    __syncthreads();

    // ---- build W_i = diag(x_i)*W_ap directly in A-fragment order ----
    // frag f = of*2+ks ; lane lc : o = of*16+(lc&15), k = ks*32+(lc>>4)*8+[0..7]
    #pragma unroll
    for (int itc = 0; itc < 2; ++itc) {
        int c  = t + itc * 256;               // 0..511
        int lc = c & 63, f = c >> 6;
        int of = f >> 1, ks = f & 1;
        int o  = of * 16 + (lc & 15);
        int k0 = ks * 32 + ((lc >> 4) << 3);
        float4 w0 = *(const float4*)(Wt + o * 64 + k0);
        float4 w1 = *(const float4*)(Wt + o * 64 + k0 + 4);
        float4 x0 = *(const float4*)(sXi + k0);
        float4 x1 = *(const float4*)(sXi + k0 + 4);
        unsigned int p0 = (unsigned int)f2bf(w0.x * x0.x) | ((unsigned int)f2bf(w0.y * x0.y) << 16);
        unsigned int p1 = (unsigned int)f2bf(w0.z * x0.z) | ((unsigned int)f2bf(w0.w * x0.w) << 16);
        unsigned int p2 = (unsigned int)f2bf(w1.x * x1.x) | ((unsigned int)f2bf(w1.y * x1.y) << 16);
        unsigned int p3 = (unsigned int)f2bf(w1.z * x1.z) | ((unsigned int)f2bf(w1.w * x1.w) << 16);
        *(int4*)(sWF + c * 16) = make_int4((int)p0, (int)p1, (int)p2, (int)p3);
    }
    __syncthreads();

    // ---- A fragments (W_i^T as MFMA-A, M=o) ----
    bf16x8 af[8];
    #pragma unroll
    for (int f = 0; f < 8; ++f)
        af[f] = *(const bf16x8*)(sWF + (f * 64 + l) * 16);

    // per-lane o-constants (o = of*16 + (l>>4)*4 + r), broadcast reads from LDS
    float n2a[16], cb[16];
    float asum = 0.f;
    #pragma unroll
    for (int of = 0; of < 4; ++of) {
        #pragma unroll
        for (int r = 0; r < 4; ++r) {
            int o = of * 16 + ((l >> 4) << 2) + r;
            float a = sAw[o];
            n2a[of * 4 + r] = -2.f * a;
            cb[of * 4 + r]  = C2LOG2E * sBp[o];
            asum += a;
        }
    }

    // ---- GEMM: S^T[o][j] = sum_k W_i[k][o] * X[j][k] ; then scores ----
    const int wbase = w << 7;   // 128 j's per wave
    #pragma unroll
    for (int jh = 0; jh < 2; ++jh) {
        f32x4 acc[4][4];
        #pragma unroll
        for (int of = 0; of < 4; ++of)
            #pragma unroll
            for (int q = 0; q < 4; ++q)
                acc[of][q] = (f32x4){0.f, 0.f, 0.f, 0.f};

        #pragma unroll
        for (int ks = 0; ks < 2; ++ks) {
            #pragma unroll
            for (int q = 0; q < 4; ++q) {
                int j = wbase + jh * 64 + q * 16 + (l & 15);
                // B-fragment straight from global: lanes {l,l+16,l+32,l+48} cover
                // one contiguous 64B half-row of X_b -> fully coalesced, L1/L2-hot
                bf16x8 bx = *(const bf16x8*)(Xg + j * 64 + ks * 32 + ((l >> 4) << 3));
                #pragma unroll
                for (int of = 0; of < 4; ++of)
                    acc[of][q] = __builtin_amdgcn_mfma_f32_16x16x32_bf16(
                        af[of * 2 + ks], bx, acc[of][q], 0, 0, 0);
            }
        }
        // score_j = sum_o a_o * tanh(S + b_o) = asum - sum_o 2 a_o / (exp2(c(S+b))+1)
        #pragma unroll
        for (int q = 0; q < 4; ++q) {
            float part = asum;
            #pragma unroll
            for (int of = 0; of < 4; ++of) {
                #pragma unroll
                for (int r = 0; r < 4; ++r) {
                    float e = EXP2F(fmaf(acc[of][q][r], C2LOG2E, cb[of * 4 + r]));
                    part = fmaf(n2a[of * 4 + r], RCPF(1.f + e), part);
                }
            }
            part += __shfl_xor(part, 16);
            part += __shfl_xor(part, 32);
            if (l < 16) sSc[wbase + jh * 64 + q * 16 + l] = part;
        }
    }
    __syncthreads();

    // ---- softmax over j (512) ----
    float s0 = sSc[t], s1 = sSc[t + 256];
    float m = fmaxf(s0, s1);
    #pragma unroll
    for (int o2 = 32; o2; o2 >>= 1) m = fmaxf(m, __shfl_xor(m, o2));
    if (l == 0) sRd[w] = m;
    __syncthreads();
    m = fmaxf(fmaxf(sRd[0], sRd[1]), fmaxf(sRd[2], sRd[3]));
    float p0 = EXP2F((s0 - m) * LOG2E);
    float p1 = EXP2F((s1 - m) * LOG2E);
    sSc[t] = p0; sSc[t + 256] = p1;
    float sm = p0 + p1;
    #pragma unroll
    for (int o2 = 32; o2; o2 >>= 1) sm += __shfl_xor(sm, o2);
    if (l == 0) sRd[4 + w] = sm;
    __syncthreads();
    float inv = RCPF(sRd[4] + sRd[5] + sRd[6] + sRd[7]);

    // ---- agg[d] = inv * sum_j p_j * x[b,j,d]  (X rows from global, coalesced) ----
    {
        int chk = t & 7, g = t >> 3;       // 8 d-chunks x 32 j-groups
        float a8[8];
        #pragma unroll
        for (int e = 0; e < 8; ++e) a8[e] = 0.f;
        #pragma unroll
        for (int jj = 0; jj < 16; ++jj) {
            int j = g * 16 + jj;
            float pj = sSc[j];
            bf16x8 v = *(const bf16x8*)(Xg + j * 64 + chk * 8);
            #pragma unroll
            for (int e = 0; e < 8; ++e)
                a8[e] = fmaf(bf2f((unsigned short)v[e]), pj, a8[e]);
        }
        float* sAP = (float*)sWF;          // reuse W-frag space (af already in regs)
        #pragma unroll
        for (int e = 0; e < 8; ++e) sAP[g * 64 + chk * 8 + e] = a8[e];
        __syncthreads();
        if (t < 64) {
            float s = 0.f;
            #pragma unroll
            for (int g2 = 0; g2 < 32; ++g2) s += sAP[g2 * 64 + t];
            sAg[t] = s * inv;
        }
    }
    __syncthreads();

    // ---- h = agg@W_pa + b_pa + x_i@W_po + b_po ; BN ; SELU ----
    if (t < 64) {
        int o = t;
        float hv = b_pa[o] + b_po[o];
        #pragma unroll 8
        for (int d = 0; d < 64; ++d) {
            hv = fmaf(sAg[d], W_pa[d * 64 + o], hv);
            hv = fmaf(sXi[d], W_po[d * 64 + o], hv);
        }
        float istd = rsqrtf(rvar[o] + 1e-5f);
        hv = (hv - rmean[o]) * istd * gma[o] + bta[o];
        const float alpha = 1.6732632423543772f, scale = 1.0507009873554805f;
        float neg = alpha * (EXP2F(hv * LOG2E) - 1.0f);
        out[((size_t)bid << 6) + o] = scale * (hv > 0.f ? hv : neg);
    }
}

extern "C" void kernel_launch(void* const* d_in, const int* in_sizes, int n_in,
                              void* d_out, int out_size, void* d_ws, size_t ws_size,
                              hipStream_t stream) {
    const float* x     = (const float*)d_in[0];
    const float* W_ap  = (const float*)d_in[1];
    const float* b_ap  = (const float*)d_in[2];
    const float* att_w = (const float*)d_in[3];
    const float* W_pa  = (const float*)d_in[4];
    const float* b_pa  = (const float*)d_in[5];
    const float* W_po  = (const float*)d_in[6];
    const float* b_po  = (const float*)d_in[7];
    const float* gma   = (const float*)d_in[8];
    const float* bta   = (const float*)d_in[9];
    const float* rmean = (const float*)d_in[10];
    const float* rvar  = (const float*)d_in[11];

    unsigned short* Xb = (unsigned short*)d_ws;              // 512 KB bf16 X
    float* Wt          = (float*)((char*)d_ws + 512 * 1024); // 16 KB W_ap^T
    float* out         = (float*)d_out;

    prep_kernel<<<128, 256, 0, stream>>>(x, W_ap, Xb, Wt);
    gat_kernel<<<4096, 256, 0, stream>>>(x, b_ap, att_w, W_pa, b_pa, W_po, b_po,
                                         gma, bta, rmean, rvar, Xb, Wt, out);
}

// Round 3
// 91.997 us; speedup vs baseline: 1.4399x; 1.4399x over previous
//
#include <hip/hip_runtime.h>
#include <cstdint>

typedef __attribute__((ext_vector_type(8))) short bf16x8;
typedef __attribute__((ext_vector_type(4))) float f32x4;

#if __has_builtin(__builtin_amdgcn_exp2f)
#define EXP2F(x) __builtin_amdgcn_exp2f(x)
#else
#define EXP2F(x) exp2f(x)
#endif
#if __has_builtin(__builtin_amdgcn_rcpf)
#define RCPF(x) __builtin_amdgcn_rcpf(x)
#else
#define RCPF(x) (1.0f/(x))
#endif

#define C2LOG2E 2.885390081777927f   // 2*log2(e)
#define LOG2E   1.4426950408889634f

__device__ __forceinline__ unsigned short f2bf(float f) {
    union { float f; unsigned int u; } v; v.f = f;
    return (unsigned short)((v.u + 0x7FFFu + ((v.u >> 16) & 1u)) >> 16);
}
__device__ __forceinline__ float bf2f(unsigned short h) {
    union { unsigned int u; float f; } v; v.u = ((unsigned int)h) << 16; return v.f;
}

// ---------------- prep: X fp32->bf16 ; W_ap transpose ----------------
__global__ void prep_kernel(const float* __restrict__ x, const float* __restrict__ W_ap,
                            unsigned short* __restrict__ Xb, float* __restrict__ Wt) {
    int t = blockIdx.x * 256 + threadIdx.x;   // 32768 threads, 8 elems each
    const float* src = x + (size_t)t * 8;
    float4 a = *(const float4*)(src);
    float4 b = *(const float4*)(src + 4);
    unsigned int p0 = (unsigned int)f2bf(a.x) | ((unsigned int)f2bf(a.y) << 16);
    unsigned int p1 = (unsigned int)f2bf(a.z) | ((unsigned int)f2bf(a.w) << 16);
    unsigned int p2 = (unsigned int)f2bf(b.x) | ((unsigned int)f2bf(b.y) << 16);
    unsigned int p3 = (unsigned int)f2bf(b.z) | ((unsigned int)f2bf(b.w) << 16);
    *(int4*)(Xb + (size_t)t * 8) = make_int4((int)p0, (int)p1, (int)p2, (int)p3);
    if (t < 64 * 64) Wt[t] = W_ap[(t & 63) * 64 + (t >> 6)];  // Wt[o][d] = W_ap[d][o]
}

// ---------------- main: one block per (b,i), X read from global (L2-hot) ----------------
// launch_bounds (256,2): R0 proved this compiles at 84 VGPR with no spill;
// (256,4) forced a 64-VGPR cap -> 326 MB of scratch traffic (R1 regression).
__global__ __launch_bounds__(256, 2) void gat_kernel(
    const float* __restrict__ x, const float* __restrict__ b_ap, const float* __restrict__ att_w,
    const float* __restrict__ W_pa, const float* __restrict__ b_pa,
    const float* __restrict__ W_po, const float* __restrict__ b_po,
    const float* __restrict__ gma, const float* __restrict__ bta,
    const float* __restrict__ rmean, const float* __restrict__ rvar,
    const unsigned short* __restrict__ Xb, const float* __restrict__ Wt,
    float* __restrict__ out)
{
    __shared__ char  sWF[8192];     // W_i MFMA A-fragments (bf16); reused as agg partials
    __shared__ float sSc[512];      // scores -> p
    __shared__ float sXi[64];
    __shared__ float sAw[64];       // att_w staged
    __shared__ float sBp[64];       // b_ap staged
    __shared__ float sAg[64];
    __shared__ float sRd[8];

    const int t = threadIdx.x;
    const int l = t & 63;
    const int w = t >> 6;
    const int bid = blockIdx.x;
    const int b = bid >> 9;
    const unsigned short* __restrict__ Xg = Xb + (size_t)b * (512 * 64);

    // ---- stage x_i, att_w, b_ap ----
    if (t < 64)            sXi[t]       = x[((size_t)bid << 6) + t];
    else if (t < 128)      sAw[t - 64]  = att_w[t - 64];
    else if (t < 192)      sBp[t - 128] = b_ap[t - 128];
    __syncthreads();

    // ---- build W_i = diag(x_i)*W_ap directly in A-fragment order ----
    // frag f = of*2+ks ; lane lc : o = of*16+(lc&15), k = ks*32+(lc>>4)*8+[0..7]
    #pragma unroll
    for (int itc = 0; itc < 2; ++itc) {
        int c  = t + itc * 256;               // 0..511
        int lc = c & 63, f = c >> 6;
        int of = f >> 1, ks = f & 1;
        int o  = of * 16 + (lc & 15);
        int k0 = ks * 32 + ((lc >> 4) << 3);
        float4 w0 = *(const float4*)(Wt + o * 64 + k0);
        float4 w1 = *(const float4*)(Wt + o * 64 + k0 + 4);
        float4 x0 = *(const float4*)(sXi + k0);
        float4 x1 = *(const float4*)(sXi + k0 + 4);
        unsigned int p0 = (unsigned int)f2bf(w0.x * x0.x) | ((unsigned int)f2bf(w0.y * x0.y) << 16);
        unsigned int p1 = (unsigned int)f2bf(w0.z * x0.z) | ((unsigned int)f2bf(w0.w * x0.w) << 16);
        unsigned int p2 = (unsigned int)f2bf(w1.x * x1.x) | ((unsigned int)f2bf(w1.y * x1.y) << 16);
        unsigned int p3 = (unsigned int)f2bf(w1.z * x1.z) | ((unsigned int)f2bf(w1.w * x1.w) << 16);
        *(int4*)(sWF + c * 16) = make_int4((int)p0, (int)p1, (int)p2, (int)p3);
    }
    __syncthreads();

    // ---- A fragments (W_i^T as MFMA-A, M=o) ----
    bf16x8 af[8];
    #pragma unroll
    for (int f = 0; f < 8; ++f)
        af[f] = *(const bf16x8*)(sWF + (f * 64 + l) * 16);

    // per-lane o-constants (o = of*16 + (l>>4)*4 + r), broadcast reads from LDS
    float n2a[16], cb[16];
    float asum = 0.f;
    #pragma unroll
    for (int of = 0; of < 4; ++of) {
        #pragma unroll
        for (int r = 0; r < 4; ++r) {
            int o = of * 16 + ((l >> 4) << 2) + r;
            float a = sAw[o];
            n2a[of * 4 + r] = -2.f * a;
            cb[of * 4 + r]  = C2LOG2E * sBp[o];
            asum += a;
        }
    }

    // ---- GEMM: S^T[o][j] = sum_k W_i[k][o] * X[j][k] ; then scores ----
    const int wbase = w << 7;   // 128 j's per wave
    #pragma unroll
    for (int jh = 0; jh < 2; ++jh) {
        f32x4 acc[4][4];
        #pragma unroll
        for (int of = 0; of < 4; ++of)
            #pragma unroll
            for (int q = 0; q < 4; ++q)
                acc[of][q] = (f32x4){0.f, 0.f, 0.f, 0.f};

        #pragma unroll
        for (int ks = 0; ks < 2; ++ks) {
            #pragma unroll
            for (int q = 0; q < 4; ++q) {
                int j = wbase + jh * 64 + q * 16 + (l & 15);
                // B-fragment straight from global: lanes {l,l+16,l+32,l+48} cover
                // one contiguous 64B half-row of X_b -> 64B segments, L1/L2-hot
                bf16x8 bx = *(const bf16x8*)(Xg + j * 64 + ks * 32 + ((l >> 4) << 3));
                #pragma unroll
                for (int of = 0; of < 4; ++of)
                    acc[of][q] = __builtin_amdgcn_mfma_f32_16x16x32_bf16(
                        af[of * 2 + ks], bx, acc[of][q], 0, 0, 0);
            }
        }
        // score_j = sum_o a_o * tanh(S + b_o) = asum - sum_o 2 a_o / (exp2(c(S+b))+1)
        #pragma unroll
        for (int q = 0; q < 4; ++q) {
            float part = asum;
            #pragma unroll
            for (int of = 0; of < 4; ++of) {
                #pragma unroll
                for (int r = 0; r < 4; ++r) {
                    float e = EXP2F(fmaf(acc[of][q][r], C2LOG2E, cb[of * 4 + r]));
                    part = fmaf(n2a[of * 4 + r], RCPF(1.f + e), part);
                }
            }
            part += __shfl_xor(part, 16);
            part += __shfl_xor(part, 32);
            if (l < 16) sSc[wbase + jh * 64 + q * 16 + l] = part;
        }
    }
    __syncthreads();

    // ---- softmax over j (512) ----
    float s0 = sSc[t], s1 = sSc[t + 256];
    float m = fmaxf(s0, s1);
    #pragma unroll
    for (int o2 = 32; o2; o2 >>= 1) m = fmaxf(m, __shfl_xor(m, o2));
    if (l == 0) sRd[w] = m;
    __syncthreads();
    m = fmaxf(fmaxf(sRd[0], sRd[1]), fmaxf(sRd[2], sRd[3]));
    float p0 = EXP2F((s0 - m) * LOG2E);
    float p1 = EXP2F((s1 - m) * LOG2E);
    sSc[t] = p0; sSc[t + 256] = p1;
    float sm = p0 + p1;
    #pragma unroll
    for (int o2 = 32; o2; o2 >>= 1) sm += __shfl_xor(sm, o2);
    if (l == 0) sRd[4 + w] = sm;
    __syncthreads();
    float inv = RCPF(sRd[4] + sRd[5] + sRd[6] + sRd[7]);

    // ---- agg[d] = inv * sum_j p_j * x[b,j,d]  (X rows from global, coalesced) ----
    {
        int chk = t & 7, g = t >> 3;       // 8 d-chunks x 32 j-groups
        float a8[8];
        #pragma unroll
        for (int e = 0; e < 8; ++e) a8[e] = 0.f;
        #pragma unroll
        for (int jj = 0; jj < 16; ++jj) {
            int j = g * 16 + jj;
            float pj = sSc[j];
            bf16x8 v = *(const bf16x8*)(Xg + j * 64 + chk * 8);
            #pragma unroll
            for (int e = 0; e < 8; ++e)
                a8[e] = fmaf(bf2f((unsigned short)v[e]), pj, a8[e]);
        }
        float* sAP = (float*)sWF;          // reuse W-frag space (af already in regs)
        #pragma unroll
        for (int e = 0; e < 8; ++e) sAP[g * 64 + chk * 8 + e] = a8[e];
        __syncthreads();
        if (t < 64) {
            float s = 0.f;
            #pragma unroll
            for (int g2 = 0; g2 < 32; ++g2) s += sAP[g2 * 64 + t];
            sAg[t] = s * inv;
        }
    }
    __syncthreads();

    // ---- h = agg@W_pa + b_pa + x_i@W_po + b_po ; BN ; SELU ----
    if (t < 64) {
        int o = t;
        float hv = b_pa[o] + b_po[o];
        #pragma unroll 8
        for (int d = 0; d < 64; ++d) {
            hv = fmaf(sAg[d], W_pa[d * 64 + o], hv);
            hv = fmaf(sXi[d], W_po[d * 64 + o], hv);
        }
        float istd = rsqrtf(rvar[o] + 1e-5f);
        hv = (hv - rmean[o]) * istd * gma[o] + bta[o];
        const float alpha = 1.6732632423543772f, scale = 1.0507009873554805f;
        float neg = alpha * (EXP2F(hv * LOG2E) - 1.0f);
        out[((size_t)bid << 6) + o] = scale * (hv > 0.f ? hv : neg);
    }
}

extern "C" void kernel_launch(void* const* d_in, const int* in_sizes, int n_in,
                              void* d_out, int out_size, void* d_ws, size_t ws_size,
                              hipStream_t stream) {
    const float* x     = (const float*)d_in[0];
    const float* W_ap  = (const float*)d_in[1];
    const float* b_ap  = (const float*)d_in[2];
    const float* att_w = (const float*)d_in[3];
    const float* W_pa  = (const float*)d_in[4];
    const float* b_pa  = (const float*)d_in[5];
    const float* W_po  = (const float*)d_in[6];
    const float* b_po  = (const float*)d_in[7];
    const float* gma   = (const float*)d_in[8];
    const float* bta   = (const float*)d_in[9];
    const float* rmean = (const float*)d_in[10];
    const float* rvar  = (const float*)d_in[11];

    unsigned short* Xb = (unsigned short*)d_ws;              // 512 KB bf16 X
    float* Wt          = (float*)((char*)d_ws + 512 * 1024); // 16 KB W_ap^T
    float* out         = (float*)d_out;

    prep_kernel<<<128, 256, 0, stream>>>(x, W_ap, Xb, Wt);
    gat_kernel<<<4096, 256, 0, stream>>>(x, b_ap, att_w, W_pa, b_pa, W_po, b_po,
                                         gma, bta, rmean, rvar, Xb, Wt, out);
}

// Round 4
// 83.389 us; speedup vs baseline: 1.5886x; 1.1032x over previous
//
#include <hip/hip_runtime.h>
#include <cstdint>

typedef __attribute__((ext_vector_type(8))) short bf16x8;
typedef __attribute__((ext_vector_type(4))) float f32x4;

#if __has_builtin(__builtin_amdgcn_exp2f)
#define EXP2F(x) __builtin_amdgcn_exp2f(x)
#else
#define EXP2F(x) exp2f(x)
#endif
#if __has_builtin(__builtin_amdgcn_rcpf)
#define RCPF(x) __builtin_amdgcn_rcpf(x)
#else
#define RCPF(x) (1.0f/(x))
#endif

#define C2LOG2E 2.885390081777927f   // 2*log2(e)
#define LOG2E   1.4426950408889634f

__device__ __forceinline__ unsigned int f2bf(float f) {
    union { float f; unsigned int u; } v; v.f = f;
    return ((v.u + 0x7FFFu + ((v.u >> 16) & 1u)) >> 16);
}

// ---------------- prep1: X fp32->bf16 ; W_ap transpose ----------------
__global__ void prep_kernel(const float* __restrict__ x, const float* __restrict__ W_ap,
                            unsigned short* __restrict__ Xb, float* __restrict__ Wt) {
    int t = blockIdx.x * 256 + threadIdx.x;   // 32768 threads, 8 elems each
    const float* src = x + (size_t)t * 8;
    float4 a = *(const float4*)(src);
    float4 b = *(const float4*)(src + 4);
    unsigned int p0 = f2bf(a.x) | (f2bf(a.y) << 16);
    unsigned int p1 = f2bf(a.z) | (f2bf(a.w) << 16);
    unsigned int p2 = f2bf(b.x) | (f2bf(b.y) << 16);
    unsigned int p3 = f2bf(b.z) | (f2bf(b.w) << 16);
    *(int4*)(Xb + (size_t)t * 8) = make_int4((int)p0, (int)p1, (int)p2, (int)p3);
    if (t < 64 * 64) Wt[t] = W_ap[(t & 63) * 64 + (t >> 6)];  // Wt[o][d] = W_ap[d][o]
}

// ---------------- prep2: Y = X@W_pa ; Z = X@W_po + b_po + b_pa ----------------
// grid = 8 b * 32 rowgroups = 256 blocks, 256 threads: row = rg*16 + t>>4, cols (t&15)*4
__global__ void prep2_kernel(const float* __restrict__ x,
                             const float* __restrict__ W_pa, const float* __restrict__ W_po,
                             const float* __restrict__ b_pa, const float* __restrict__ b_po,
                             float* __restrict__ Y, float* __restrict__ Z) {
    int blk = blockIdx.x, b = blk >> 5, rg = blk & 31, t = threadIdx.x;
    int r = rg * 16 + (t >> 4);
    int c = (t & 15) * 4;
    const float* xr = x + ((size_t)b * 512 + r) * 64;
    float4 ay = {0.f, 0.f, 0.f, 0.f}, az = {0.f, 0.f, 0.f, 0.f};
    #pragma unroll 8
    for (int d = 0; d < 64; ++d) {
        float xv = xr[d];
        float4 wa = *(const float4*)(W_pa + d * 64 + c);
        float4 wo = *(const float4*)(W_po + d * 64 + c);
        ay.x = fmaf(xv, wa.x, ay.x); ay.y = fmaf(xv, wa.y, ay.y);
        ay.z = fmaf(xv, wa.z, ay.z); ay.w = fmaf(xv, wa.w, ay.w);
        az.x = fmaf(xv, wo.x, az.x); az.y = fmaf(xv, wo.y, az.y);
        az.z = fmaf(xv, wo.z, az.z); az.w = fmaf(xv, wo.w, az.w);
    }
    float4 bb = *(const float4*)(b_pa + c);
    float4 bo = *(const float4*)(b_po + c);
    az.x += bb.x + bo.x; az.y += bb.y + bo.y; az.z += bb.z + bo.z; az.w += bb.w + bo.w;
    size_t o = ((size_t)b * 512 + r) * 64 + c;
    *(float4*)(Y + o) = ay;
    *(float4*)(Z + o) = az;
}

// ---------------- main: one WAVE per (b,i), barrier-free ----------------
__global__ __launch_bounds__(256) void gat_kernel(
    const float* __restrict__ x, const float* __restrict__ b_ap, const float* __restrict__ att_w,
    const float* __restrict__ gma, const float* __restrict__ bta,
    const float* __restrict__ rmean, const float* __restrict__ rvar,
    const unsigned short* __restrict__ Xb, const float* __restrict__ Wt,
    const float* __restrict__ Y, const float* __restrict__ Z,
    float* __restrict__ out)
{
    __shared__ float sSc[4 * 512];   // per-wave score/p slices
    __shared__ float sAg[4 * 64];    // per-wave agg slices

    const int t  = threadIdx.x;
    const int l  = t & 63;
    const int w  = t >> 6;
    const int ig = blockIdx.x * 4 + w;          // global i in [0,4096)
    const int b  = ig >> 9;
    const int lm = l & 15;                       // col-in-tile
    const int lq = l >> 4;                       // quarter
    const unsigned short* __restrict__ Xg = Xb + (size_t)b * (512 * 64);
    float* mySc = sSc + w * 512;

    // ---- build A-fragments (W_i^T) fully in-register ----
    // af[of*2+ks][e] = bf16( Wt[(of*16+lm)*64 + ks*32 + lq*8 + e] * x_i[ks*32 + lq*8 + e] )
    bf16x8 af[8];
    const float* xi = x + (size_t)ig * 64;
    #pragma unroll
    for (int ks = 0; ks < 2; ++ks) {
        float4 xc0 = *(const float4*)(xi + ks * 32 + lq * 8);
        float4 xc1 = *(const float4*)(xi + ks * 32 + lq * 8 + 4);
        #pragma unroll
        for (int of = 0; of < 4; ++of) {
            const float* wr = Wt + (of * 16 + lm) * 64 + ks * 32 + lq * 8;
            float4 w0 = *(const float4*)(wr);
            float4 w1 = *(const float4*)(wr + 4);
            unsigned int p0 = f2bf(w0.x * xc0.x) | (f2bf(w0.y * xc0.y) << 16);
            unsigned int p1 = f2bf(w0.z * xc0.z) | (f2bf(w0.w * xc0.w) << 16);
            unsigned int p2 = f2bf(w1.x * xc1.x) | (f2bf(w1.y * xc1.y) << 16);
            unsigned int p3 = f2bf(w1.z * xc1.z) | (f2bf(w1.w * xc1.w) << 16);
            int4 pk = make_int4((int)p0, (int)p1, (int)p2, (int)p3);
            af[of * 2 + ks] = *reinterpret_cast<bf16x8*>(&pk);
        }
    }

    // ---- per-lane o-constants (o = of*16 + lq*4 + r) ----
    float n2a[16], cb[16];
    float asum = 0.f;
    #pragma unroll
    for (int of = 0; of < 4; ++of) {
        #pragma unroll
        for (int r = 0; r < 4; ++r) {
            int o = of * 16 + lq * 4 + r;
            float a = att_w[o];
            n2a[of * 4 + r] = -2.f * a;
            cb[of * 4 + r]  = C2LOG2E * b_ap[o];
            asum += a;
        }
    }

    // ---- GEMM + tanh-score over 32 j-tiles ----
    #pragma unroll 2
    for (int jt = 0; jt < 32; ++jt) {
        f32x4 acc[4];
        #pragma unroll
        for (int of = 0; of < 4; ++of) acc[of] = (f32x4){0.f, 0.f, 0.f, 0.f};
        #pragma unroll
        for (int ks = 0; ks < 2; ++ks) {
            bf16x8 bx = *(const bf16x8*)(Xg + (jt * 16 + lm) * 64 + ks * 32 + lq * 8);
            #pragma unroll
            for (int of = 0; of < 4; ++of)
                acc[of] = __builtin_amdgcn_mfma_f32_16x16x32_bf16(af[of * 2 + ks], bx, acc[of], 0, 0, 0);
        }
        float part = asum;
        #pragma unroll
        for (int of = 0; of < 4; ++of) {
            #pragma unroll
            for (int r = 0; r < 4; ++r) {
                float e = EXP2F(fmaf(acc[of][r], C2LOG2E, cb[of * 4 + r]));
                part = fmaf(n2a[of * 4 + r], RCPF(1.f + e), part);
            }
        }
        part += __shfl_xor(part, 16);
        part += __shfl_xor(part, 32);
        if (l < 16) mySc[jt * 16 + l] = part;
    }
    asm volatile("s_waitcnt lgkmcnt(0)" ::: "memory");   // wave-private RAW on mySc

    // ---- wave-private softmax over 512 ----
    float s0[8];
    {
        float4 r0 = *(const float4*)(mySc + l * 8);
        float4 r1 = *(const float4*)(mySc + l * 8 + 4);
        s0[0] = r0.x; s0[1] = r0.y; s0[2] = r0.z; s0[3] = r0.w;
        s0[4] = r1.x; s0[5] = r1.y; s0[6] = r1.z; s0[7] = r1.w;
    }
    float m = s0[0];
    #pragma unroll
    for (int e = 1; e < 8; ++e) m = fmaxf(m, s0[e]);
    #pragma unroll
    for (int o2 = 32; o2; o2 >>= 1) m = fmaxf(m, __shfl_xor(m, o2));
    float sm = 0.f;
    #pragma unroll
    for (int e = 0; e < 8; ++e) { s0[e] = EXP2F((s0[e] - m) * LOG2E); sm += s0[e]; }
    #pragma unroll
    for (int o2 = 32; o2; o2 >>= 1) sm += __shfl_xor(sm, o2);
    float inv = RCPF(sm);
    {
        float4 r0 = {s0[0] * inv, s0[1] * inv, s0[2] * inv, s0[3] * inv};
        float4 r1 = {s0[4] * inv, s0[5] * inv, s0[6] * inv, s0[7] * inv};
        *(float4*)(mySc + l * 8) = r0;
        *(float4*)(mySc + l * 8 + 4) = r1;
    }
    asm volatile("s_waitcnt lgkmcnt(0)" ::: "memory");

    // ---- h-partial: hagg[o] = sum_j p_j * Y[b,j,o]  (lane = 8 rows x 8 col-chunks) ----
    {
        const int rs = l >> 3, c8 = (l & 7) * 8;
        const float* Yb = Y + (size_t)b * (512 * 64);
        float a8[8];
        #pragma unroll
        for (int e = 0; e < 8; ++e) a8[e] = 0.f;
        #pragma unroll 4
        for (int jb = 0; jb < 64; ++jb) {
            int j = jb * 8 + rs;
            float pj = mySc[j];
            const float* yr = Yb + j * 64 + c8;
            float4 y0 = *(const float4*)(yr);
            float4 y1 = *(const float4*)(yr + 4);
            a8[0] = fmaf(pj, y0.x, a8[0]); a8[1] = fmaf(pj, y0.y, a8[1]);
            a8[2] = fmaf(pj, y0.z, a8[2]); a8[3] = fmaf(pj, y0.w, a8[3]);
            a8[4] = fmaf(pj, y1.x, a8[4]); a8[5] = fmaf(pj, y1.y, a8[5]);
            a8[6] = fmaf(pj, y1.z, a8[6]); a8[7] = fmaf(pj, y1.w, a8[7]);
        }
        #pragma unroll
        for (int e = 0; e < 8; ++e) {
            float v = a8[e];
            v += __shfl_xor(v, 8);
            v += __shfl_xor(v, 16);
            v += __shfl_xor(v, 32);
            a8[e] = v;
        }
        if (l < 8) {
            #pragma unroll
            for (int e = 0; e < 8; ++e) sAg[w * 64 + l * 8 + e] = a8[e];
        }
    }
    asm volatile("s_waitcnt lgkmcnt(0)" ::: "memory");

    // ---- epilogue: h = hagg + Z[i,:]; BN; SELU ----
    {
        float hv = sAg[w * 64 + l] + Z[(size_t)ig * 64 + l];
        float istd = rsqrtf(rvar[l] + 1e-5f);
        hv = (hv - rmean[l]) * istd * gma[l] + bta[l];
        const float alpha = 1.6732632423543772f, scale = 1.0507009873554805f;
        float neg = alpha * (EXP2F(hv * LOG2E) - 1.0f);
        out[(size_t)ig * 64 + l] = scale * (hv > 0.f ? hv : neg);
    }
}

extern "C" void kernel_launch(void* const* d_in, const int* in_sizes, int n_in,
                              void* d_out, int out_size, void* d_ws, size_t ws_size,
                              hipStream_t stream) {
    const float* x     = (const float*)d_in[0];
    const float* W_ap  = (const float*)d_in[1];
    const float* b_ap  = (const float*)d_in[2];
    const float* att_w = (const float*)d_in[3];
    const float* W_pa  = (const float*)d_in[4];
    const float* b_pa  = (const float*)d_in[5];
    const float* W_po  = (const float*)d_in[6];
    const float* b_po  = (const float*)d_in[7];
    const float* gma   = (const float*)d_in[8];
    const float* bta   = (const float*)d_in[9];
    const float* rmean = (const float*)d_in[10];
    const float* rvar  = (const float*)d_in[11];

    char* ws = (char*)d_ws;
    unsigned short* Xb = (unsigned short*)ws;                    // 512 KB bf16 X
    float* Wt          = (float*)(ws + 512 * 1024);              // 16 KB W_ap^T
    float* Y           = (float*)(ws + 528 * 1024);              // 1 MB  X@W_pa
    float* Zt          = (float*)(ws + 528 * 1024 + 1024 * 1024);// 1 MB  X@W_po + biases
    float* out         = (float*)d_out;

    prep_kernel<<<128, 256, 0, stream>>>(x, W_ap, Xb, Wt);
    prep2_kernel<<<256, 256, 0, stream>>>(x, W_pa, W_po, b_pa, b_po, Y, Zt);
    gat_kernel<<<1024, 256, 0, stream>>>(x, b_ap, att_w, gma, bta, rmean, rvar,
                                         Xb, Wt, Y, Zt, out);
}

// Round 5
// 74.718 us; speedup vs baseline: 1.7729x; 1.1160x over previous
//
#include <hip/hip_runtime.h>
#include <cstdint>

typedef __attribute__((ext_vector_type(8))) short bf16x8;
typedef __attribute__((ext_vector_type(4))) float f32x4;

#if __has_builtin(__builtin_amdgcn_exp2f)
#define EXP2F(x) __builtin_amdgcn_exp2f(x)
#else
#define EXP2F(x) exp2f(x)
#endif
#if __has_builtin(__builtin_amdgcn_rcpf)
#define RCPF(x) __builtin_amdgcn_rcpf(x)
#else
#define RCPF(x) (1.0f/(x))
#endif

#define C2LOG2E 2.885390081777927f   // 2*log2(e)
#define LOG2E   1.4426950408889634f

__device__ __forceinline__ unsigned int f2bf(float f) {
    union { float f; unsigned int u; } v; v.f = f;
    return ((v.u + 0x7FFFu + ((v.u >> 16) & 1u)) >> 16);
}
__device__ __forceinline__ float bf2f(unsigned short h) {
    union { unsigned int u; float f; } v; v.u = ((unsigned int)h) << 16; return v.f;
}

// ---- prep: X fp32->bf16 ; transpose W_ap, W_pa, W_po ----
__global__ void prep_kernel(const float* __restrict__ x, const float* __restrict__ W_ap,
                            const float* __restrict__ W_pa, const float* __restrict__ W_po,
                            unsigned short* __restrict__ Xb, float* __restrict__ Wt,
                            float* __restrict__ Wpat, float* __restrict__ Wpot) {
    int t = blockIdx.x * 256 + threadIdx.x;   // 32768 threads, 8 elems each
    const float* src = x + (size_t)t * 8;
    float4 a = *(const float4*)(src);
    float4 b = *(const float4*)(src + 4);
    unsigned int p0 = f2bf(a.x) | (f2bf(a.y) << 16);
    unsigned int p1 = f2bf(a.z) | (f2bf(a.w) << 16);
    unsigned int p2 = f2bf(b.x) | (f2bf(b.y) << 16);
    unsigned int p3 = f2bf(b.z) | (f2bf(b.w) << 16);
    *(int4*)(Xb + (size_t)t * 8) = make_int4((int)p0, (int)p1, (int)p2, (int)p3);
    if (t < 64 * 64) {
        int src_i = (t & 63) * 64 + (t >> 6);   // [d][o] -> [o][d]
        Wt[t]   = W_ap[src_i];
        Wpat[t] = W_pa[src_i];
        Wpot[t] = W_po[src_i];
    }
}

// ---- main: one 64-lane WAVE per (b,i); single-wave blocks, barrier-free ----
__global__ __launch_bounds__(64, 4) void gat_kernel(
    const float* __restrict__ x, const float* __restrict__ b_ap, const float* __restrict__ att_w,
    const float* __restrict__ b_pa, const float* __restrict__ b_po,
    const float* __restrict__ gma, const float* __restrict__ bta,
    const float* __restrict__ rmean, const float* __restrict__ rvar,
    const unsigned short* __restrict__ Xb, const float* __restrict__ Wt,
    const float* __restrict__ Wpat, const float* __restrict__ Wpot,
    float* __restrict__ out)
{
    __shared__ float sSc[512];
    __shared__ float sAg[64];

    const int l  = threadIdx.x;
    const int ig = blockIdx.x;                 // global i in [0,4096)
    const int b  = ig >> 9;
    const int lm = l & 15;                     // col-in-tile
    const int lq = l >> 4;                     // quarter
    const unsigned short* __restrict__ Xg = Xb + (size_t)b * (512 * 64);
    const float* __restrict__ xi = x + (size_t)ig * 64;

    // ---- A-fragments (W_i^T) in-register ----
    bf16x8 af[8];
    #pragma unroll
    for (int ks = 0; ks < 2; ++ks) {
        float4 xc0 = *(const float4*)(xi + ks * 32 + lq * 8);
        float4 xc1 = *(const float4*)(xi + ks * 32 + lq * 8 + 4);
        #pragma unroll
        for (int of = 0; of < 4; ++of) {
            const float* wr = Wt + (of * 16 + lm) * 64 + ks * 32 + lq * 8;
            float4 w0 = *(const float4*)(wr);
            float4 w1 = *(const float4*)(wr + 4);
            unsigned int p0 = f2bf(w0.x * xc0.x) | (f2bf(w0.y * xc0.y) << 16);
            unsigned int p1 = f2bf(w0.z * xc0.z) | (f2bf(w0.w * xc0.w) << 16);
            unsigned int p2 = f2bf(w1.x * xc1.x) | (f2bf(w1.y * xc1.y) << 16);
            unsigned int p3 = f2bf(w1.z * xc1.z) | (f2bf(w1.w * xc1.w) << 16);
            int4 pk = make_int4((int)p0, (int)p1, (int)p2, (int)p3);
            af[of * 2 + ks] = *reinterpret_cast<bf16x8*>(&pk);
        }
    }

    // ---- per-lane o-constants (o = of*16 + lq*4 + r) ----
    float n2a[16], cb[16];
    float asum = 0.f;
    #pragma unroll
    for (int of = 0; of < 4; ++of) {
        #pragma unroll
        for (int r = 0; r < 4; ++r) {
            int o = of * 16 + lq * 4 + r;
            float a = att_w[o];
            n2a[of * 4 + r] = -2.f * a;
            cb[of * 4 + r]  = C2LOG2E * b_ap[o];
            asum += a;
        }
    }

    // ---- GEMM + tanh-score, 32 j-tiles, next-tile prefetch ----
    const unsigned short* xrow = Xg + lm * 64 + lq * 8;
    bf16x8 nb0 = *(const bf16x8*)(xrow);
    bf16x8 nb1 = *(const bf16x8*)(xrow + 32);
    for (int jt = 0; jt < 32; ++jt) {
        bf16x8 b0 = nb0, b1 = nb1;
        if (jt < 31) {
            nb0 = *(const bf16x8*)(xrow + (jt + 1) * 1024);
            nb1 = *(const bf16x8*)(xrow + (jt + 1) * 1024 + 32);
        }
        f32x4 acc[4];
        #pragma unroll
        for (int of = 0; of < 4; ++of) {
            acc[of] = (f32x4){0.f, 0.f, 0.f, 0.f};
            acc[of] = __builtin_amdgcn_mfma_f32_16x16x32_bf16(af[of * 2],     b0, acc[of], 0, 0, 0);
            acc[of] = __builtin_amdgcn_mfma_f32_16x16x32_bf16(af[of * 2 + 1], b1, acc[of], 0, 0, 0);
        }
        // 4 independent accumulation chains (break the 16-deep serial fma chain)
        float p4[4];
        #pragma unroll
        for (int of = 0; of < 4; ++of) {
            float pp = 0.f;
            #pragma unroll
            for (int r = 0; r < 4; ++r) {
                float e = EXP2F(fmaf(acc[of][r], C2LOG2E, cb[of * 4 + r]));
                pp = fmaf(n2a[of * 4 + r], RCPF(1.f + e), pp);
            }
            p4[of] = pp;
        }
        float part = asum + ((p4[0] + p4[1]) + (p4[2] + p4[3]));
        part += __shfl_xor(part, 16);
        part += __shfl_xor(part, 32);
        if (l < 16) sSc[jt * 16 + l] = part;
    }
    asm volatile("s_waitcnt lgkmcnt(0)" ::: "memory");   // wave-private RAW on sSc

    // ---- wave-private softmax over 512 ----
    float s0[8];
    {
        float4 r0 = *(const float4*)(sSc + l * 8);
        float4 r1 = *(const float4*)(sSc + l * 8 + 4);
        s0[0] = r0.x; s0[1] = r0.y; s0[2] = r0.z; s0[3] = r0.w;
        s0[4] = r1.x; s0[5] = r1.y; s0[6] = r1.z; s0[7] = r1.w;
    }
    float m = s0[0];
    #pragma unroll
    for (int e = 1; e < 8; ++e) m = fmaxf(m, s0[e]);
    #pragma unroll
    for (int o2 = 32; o2; o2 >>= 1) m = fmaxf(m, __shfl_xor(m, o2));
    float sm = 0.f;
    #pragma unroll
    for (int e = 0; e < 8; ++e) { s0[e] = EXP2F((s0[e] - m) * LOG2E); sm += s0[e]; }
    #pragma unroll
    for (int o2 = 32; o2; o2 >>= 1) sm += __shfl_xor(sm, o2);
    float inv = RCPF(sm);
    {
        float4 r0 = {s0[0] * inv, s0[1] * inv, s0[2] * inv, s0[3] * inv};
        float4 r1 = {s0[4] * inv, s0[5] * inv, s0[6] * inv, s0[7] * inv};
        *(float4*)(sSc + l * 8) = r0;
        *(float4*)(sSc + l * 8 + 4) = r1;
    }
    asm volatile("s_waitcnt lgkmcnt(0)" ::: "memory");

    // ---- agg[d] = sum_j p_j * x[b,j,d]  (bf16 X, L1-hot from QK phase) ----
    {
        const int rs = l >> 3, c8 = (l & 7) * 8;
        float a8[8];
        #pragma unroll
        for (int e = 0; e < 8; ++e) a8[e] = 0.f;
        #pragma unroll 4
        for (int jb = 0; jb < 64; ++jb) {
            int j = jb * 8 + rs;
            float pj = sSc[j];
            bf16x8 v = *(const bf16x8*)(Xg + j * 64 + c8);
            #pragma unroll
            for (int e = 0; e < 8; ++e)
                a8[e] = fmaf(bf2f((unsigned short)v[e]), pj, a8[e]);
        }
        #pragma unroll
        for (int e = 0; e < 8; ++e) {
            float v = a8[e];
            v += __shfl_xor(v, 8);
            v += __shfl_xor(v, 16);
            v += __shfl_xor(v, 32);
            a8[e] = v;
        }
        if (l < 8) {
            #pragma unroll
            for (int e = 0; e < 8; ++e) sAg[l * 8 + e] = a8[e];
        }
    }
    asm volatile("s_waitcnt lgkmcnt(0)" ::: "memory");

    // ---- epilogue: h[o=l] = agg@W_pa + x_i@W_po + biases ; BN ; SELU ----
    {
        float hv = b_pa[l] + b_po[l];
        const float* wa = Wpat + l * 64;
        const float* wo = Wpot + l * 64;
        #pragma unroll 4
        for (int dc = 0; dc < 16; ++dc) {
            float4 ag = *(const float4*)(sAg + dc * 4);   // LDS broadcast
            float4 va = *(const float4*)(wa + dc * 4);
            float4 vo = *(const float4*)(wo + dc * 4);
            float4 xv = *(const float4*)(xi + dc * 4);    // global broadcast, L1
            hv = fmaf(ag.x, va.x, hv); hv = fmaf(ag.y, va.y, hv);
            hv = fmaf(ag.z, va.z, hv); hv = fmaf(ag.w, va.w, hv);
            hv = fmaf(xv.x, vo.x, hv); hv = fmaf(xv.y, vo.y, hv);
            hv = fmaf(xv.z, vo.z, hv); hv = fmaf(xv.w, vo.w, hv);
        }
        float istd = rsqrtf(rvar[l] + 1e-5f);
        hv = (hv - rmean[l]) * istd * gma[l] + bta[l];
        const float alpha = 1.6732632423543772f, scale = 1.0507009873554805f;
        float neg = alpha * (EXP2F(hv * LOG2E) - 1.0f);
        out[(size_t)ig * 64 + l] = scale * (hv > 0.f ? hv : neg);
    }
}

extern "C" void kernel_launch(void* const* d_in, const int* in_sizes, int n_in,
                              void* d_out, int out_size, void* d_ws, size_t ws_size,
                              hipStream_t stream) {
    const float* x     = (const float*)d_in[0];
    const float* W_ap  = (const float*)d_in[1];
    const float* b_ap  = (const float*)d_in[2];
    const float* att_w = (const float*)d_in[3];
    const float* W_pa  = (const float*)d_in[4];
    const float* b_pa  = (const float*)d_in[5];
    const float* W_po  = (const float*)d_in[6];
    const float* b_po  = (const float*)d_in[7];
    const float* gma   = (const float*)d_in[8];
    const float* bta   = (const float*)d_in[9];
    const float* rmean = (const float*)d_in[10];
    const float* rvar  = (const float*)d_in[11];

    char* ws = (char*)d_ws;
    unsigned short* Xb = (unsigned short*)ws;          // 512 KB bf16 X
    float* Wt          = (float*)(ws + 512 * 1024);    // 16 KB W_ap^T
    float* Wpat        = (float*)(ws + 528 * 1024);    // 16 KB W_pa^T
    float* Wpot        = (float*)(ws + 544 * 1024);    // 16 KB W_po^T
    float* out         = (float*)d_out;

    prep_kernel<<<128, 256, 0, stream>>>(x, W_ap, W_pa, W_po, Xb, Wt, Wpat, Wpot);
    gat_kernel<<<4096, 64, 0, stream>>>(x, b_ap, att_w, b_pa, b_po, gma, bta, rmean, rvar,
                                        Xb, Wt, Wpat, Wpot, out);
}